// Round 1
// baseline (2105.689 us; speedup 1.0000x reference)
//
#include <hip/hip_runtime.h>
#include <math.h>

namespace {
constexpr int INN   = 512;
constexpr int HIDN  = 1024;
constexpr int LAY   = 2048;
constexpr int NBLK  = 256;           // blocks per step kernel
constexpr int TPB   = 256;           // 4 waves
constexpr int RPB   = LAY / NBLK;    // 8 rows per block
constexpr int WVS   = TPB / 64;      // 4 waves
constexpr int RPW   = RPB / WVS;     // 2 rows per wave
constexpr int NITER = 512;
constexpr float EPS = 1e-12f;

__global__ void init_act(const float* __restrict__ x, float* __restrict__ act) {
  int i = blockIdx.x * blockDim.x + threadIdx.x;
  if (i < LAY) act[i] = (i < INN) ? x[i] : 0.0f;
}

// One iteration: y = relu(W @ act); y[:512] = x; hidden stored UN-normalized.
// Normalization of the hidden part is deferred: each block recomputes
// inv_norm from the stored (un-normalized) hidden vector and folds it into
// the dot product:  y[j] = sum_{k<1024} a[k]W[j,k] + inv * sum_{k>=1024} h[k]W[j,k]
__global__ __launch_bounds__(TPB) void step_kernel(
    const float* __restrict__ x, const float* __restrict__ W,
    const float* __restrict__ act_in, float* __restrict__ act_out) {
  __shared__ float s_act[LAY];
  __shared__ float s_red[WVS];
  const int tid = threadIdx.x;
  const int wv  = tid >> 6;
  const int ln  = tid & 63;

  // stage act vector (8 KB) into LDS, vectorized float4
  {
    const float4* a4 = reinterpret_cast<const float4*>(act_in);
    float4* s4 = reinterpret_cast<float4*>(s_act);
#pragma unroll
    for (int i = 0; i < LAY / 4 / TPB; ++i)
      s4[tid + i * TPB] = a4[tid + i * TPB];
  }
  __syncthreads();

  // sum of squares of hidden part (redundant per block; ~4 MACs/thread)
  float ss = 0.0f;
#pragma unroll
  for (int i = 0; i < HIDN / TPB; ++i) {
    float v = s_act[LAY - HIDN + tid + i * TPB];
    ss = fmaf(v, v, ss);
  }
#pragma unroll
  for (int off = 1; off < 64; off <<= 1) ss += __shfl_xor(ss, off, 64);
  if (ln == 0) s_red[wv] = ss;
  __syncthreads();
  float sst = 0.0f;
#pragma unroll
  for (int i = 0; i < WVS; ++i) sst += s_red[i];
  const float inv = 1.0f / fmaxf(sqrtf(sst), EPS);

  // matvec: each wave owns RPW rows; lane ln strides k by 64 (coalesced W reads)
#pragma unroll
  for (int r = 0; r < RPW; ++r) {
    const int row = blockIdx.x * RPB + wv * RPW + r;
    const float* __restrict__ wr = W + (size_t)row * LAY;
    float a0 = 0.0f, a1 = 0.0f;
#pragma unroll
    for (int i = 0; i < 16; ++i)            // k in [0,1024): x + y region
      a0 = fmaf(wr[ln + i * 64], s_act[ln + i * 64], a0);
#pragma unroll
    for (int i = 16; i < 32; ++i)           // k in [1024,2048): hidden region
      a1 = fmaf(wr[ln + i * 64], s_act[ln + i * 64], a1);
    float y = fmaf(inv, a1, a0);
#pragma unroll
    for (int off = 1; off < 64; off <<= 1) y += __shfl_xor(y, off, 64);
    if (ln == 0) {
      float v = fmaxf(y, 0.0f);
      if (row < INN) v = x[row];            // clamp visible input
      act_out[row] = v;
    }
  }
}

// Write final output: visible + y parts as-is, hidden normalized.
__global__ __launch_bounds__(TPB) void final_kernel(
    const float* __restrict__ act, float* __restrict__ out) {
  __shared__ float s_red[WVS];
  const int tid = threadIdx.x;
  float ss = 0.0f;
  for (int i = tid; i < HIDN; i += TPB) {
    float v = act[LAY - HIDN + i];
    ss = fmaf(v, v, ss);
  }
  for (int off = 1; off < 64; off <<= 1) ss += __shfl_xor(ss, off, 64);
  if ((tid & 63) == 0) s_red[tid >> 6] = ss;
  __syncthreads();
  float sst = 0.0f;
  for (int i = 0; i < WVS; ++i) sst += s_red[i];
  const float inv = 1.0f / fmaxf(sqrtf(sst), EPS);
  for (int i = tid; i < LAY; i += TPB) {
    float v = act[i];
    out[i] = (i < LAY - HIDN) ? v : v * inv;
  }
}
} // namespace

extern "C" void kernel_launch(void* const* d_in, const int* in_sizes, int n_in,
                              void* d_out, int out_size, void* d_ws, size_t ws_size,
                              hipStream_t stream) {
  const float* x = (const float*)d_in[0];
  // d_in[1] is y: only used as zeros_like in the reference -> unused here.
  const float* W = (const float*)d_in[2];
  // d_in[3] is n == 512 (fixed by the problem).
  float* out  = (float*)d_out;
  float* act0 = (float*)d_ws;         // ping
  float* act1 = act0 + LAY;           // pong  (16 KB total of d_ws)

  init_act<<<dim3((LAY + 255) / 256), dim3(256), 0, stream>>>(x, act0);
  for (int t = 0; t < NITER; ++t) {
    const float* ai = (t & 1) ? act1 : act0;
    float*       ao = (t & 1) ? act0 : act1;
    step_kernel<<<dim3(NBLK), dim3(TPB), 0, stream>>>(x, W, ai, ao);
  }
  // NITER even -> final activations are in act0
  final_kernel<<<dim3(1), dim3(TPB), 0, stream>>>(act0, out);
}